// Round 1
// baseline (399.211 us; speedup 1.0000x reference)
//
#include <hip/hip_runtime.h>

// Problem constants (fixed by the reference's setup_inputs).
constexpr int B  = 128;          // B_IMG * P * P = 32*2*2
constexpr int C  = 128;
constexpr int H  = 56, W = 56;
constexpr int HO = H + 2, WO = W + 2;        // 58 x 58
constexpr int PLANE_IN  = H * W;             // 3136
constexpr int PLANE_OUT = HO * WO;           // 3364

__global__ __launch_bounds__(256) void pad2d_kernel(
    const float* __restrict__ x,
    const float* __restrict__ topW, const float* __restrict__ botW,
    const float* __restrict__ leftW, const float* __restrict__ rightW,
    const float* __restrict__ tlW,  const float* __restrict__ trW,
    const float* __restrict__ blW,  const float* __restrict__ brW,
    const int* __restrict__ np_ptr,
    float* __restrict__ out)
{
    const int plane = blockIdx.x;            // 0 .. B*C-1
    const int b   = plane / C;               // batch index
    const int c   = plane - b * C;           // channel
    const int tid = threadIdx.x;

    const int Pn = *np_ptr;                  // 2
    const int within = b % (Pn * Pn);
    const bool top_z   = within < Pn;
    const bool bot_z   = within >= Pn * Pn - Pn;
    const bool left_z  = (b % Pn) == 0;
    const bool right_z = (b % Pn) == Pn - 1;

    const float* __restrict__ xin = x + (size_t)plane * PLANE_IN;
    float* __restrict__ o = out + (size_t)plane * PLANE_OUT;

    // ---- Interior copy: 56 rows x 14 float4 (aligned reads) ----
    const float4* __restrict__ x4 = (const float4*)xin;
    constexpr int NV = H * (W / 4);          // 784 float4 per plane
    for (int i = tid; i < NV; i += 256) {
        const int r = i / 14;                // input row
        const int q = i - r * 14;            // float4 index within row
        const float4 v = x4[i];
        float* dst = o + (r + 1) * WO + 1 + q * 4;   // odd col offset -> scalar stores
        dst[0] = v.x; dst[1] = v.y; dst[2] = v.z; dst[3] = v.w;
    }

    // ---- Boundary: 228 elements, one per thread (tid < 228) ----
    if (tid < 228) {
        if (tid < 56) {                      // top row, out col = tid+1
            const int col = tid;
            const float v = top_z ? 0.f
                : topW[c] * (xin[col] + xin[W + col]);
            o[col + 1] = v;
        } else if (tid < 112) {              // bottom row
            const int col = tid - 56;
            const float v = bot_z ? 0.f
                : botW[c] * (xin[(H - 2) * W + col] + xin[(H - 1) * W + col]);
            o[(HO - 1) * WO + col + 1] = v;
        } else if (tid < 168) {              // left col, out row = r+1
            const int r = tid - 112;
            const float v = left_z ? 0.f
                : leftW[c] * (xin[r * W] + xin[r * W + 1]);
            o[(r + 1) * WO] = v;
        } else if (tid < 224) {              // right col
            const int r = tid - 168;
            const float v = right_z ? 0.f
                : rightW[c] * (xin[r * W + W - 2] + xin[r * W + W - 1]);
            o[(r + 1) * WO + WO - 1] = v;
        } else if (tid == 224) {             // top-left corner
            o[0] = (top_z || left_z) ? 0.f : tlW[c] * xin[0];
        } else if (tid == 225) {             // top-right
            o[WO - 1] = (top_z || right_z) ? 0.f : trW[c] * xin[W - 1];
        } else if (tid == 226) {             // bottom-left
            o[(HO - 1) * WO] = (bot_z || left_z) ? 0.f : blW[c] * xin[(H - 1) * W];
        } else {                             // tid == 227, bottom-right
            o[(HO - 1) * WO + WO - 1] =
                (bot_z || right_z) ? 0.f : brW[c] * xin[(H - 1) * W + W - 1];
        }
    }
}

extern "C" void kernel_launch(void* const* d_in, const int* in_sizes, int n_in,
                              void* d_out, int out_size, void* d_ws, size_t ws_size,
                              hipStream_t stream) {
    const float* x      = (const float*)d_in[0];
    const float* topW   = (const float*)d_in[1];
    const float* botW   = (const float*)d_in[2];
    const float* leftW  = (const float*)d_in[3];
    const float* rightW = (const float*)d_in[4];
    const float* tlW    = (const float*)d_in[5];
    const float* trW    = (const float*)d_in[6];
    const float* blW    = (const float*)d_in[7];
    const float* brW    = (const float*)d_in[8];
    // d_in[9] = padding (fixed 1), d_in[10] = num_patches
    const int* np_ptr   = (const int*)d_in[10];
    float* out = (float*)d_out;

    pad2d_kernel<<<dim3(B * C), dim3(256), 0, stream>>>(
        x, topW, botW, leftW, rightW, tlW, trW, blW, brW, np_ptr, out);
}